// Round 6
// baseline (186.065 us; speedup 1.0000x reference)
//
#include <hip/hip_runtime.h>
#include <math.h>

#define B 4
#define N 4096
#define M 8192
#define C 64
#define NB 2048
#define XMIN (-64.0f)
#define INV_BW 16.0f   // bucket width 0.0625
#define CUT 10.0f      // truncation at exp(-10): err ~0.008 << tolerance
#define QG2 32         // queries per gather group (2 MFMA M-tiles)
#define NSUBP 4        // point sub-blocks per batch (2048 elems each)
#define NSUBQ 2        // query sub-blocks per batch (2048 elems each)
#define GRID 256
#define TPB 512

typedef __attribute__((ext_vector_type(8))) short short8;   // 8 bf16
typedef __attribute__((ext_vector_type(4))) float f32x4;

__device__ __forceinline__ int bucket_of(float v) {
    int k = (int)floorf((v - XMIN) * INV_BW);
    return min(max(k, 0), NB - 1);
}

__device__ __forceinline__ unsigned short f2bf(float f) {   // RNE fp32->bf16
    unsigned int u = __float_as_uint(f);
    return (unsigned short)((u + 0x7FFF + ((u >> 16) & 1)) >> 16);
}

// Device-scope grid barrier: one monotonically-increasing counter, cumulative
// targets -> no reset race. Counter zeroed by hipMemsetAsync before launch.
// G16: agent-scope atomics + fences are the sanctioned cross-XCD mechanism.
__device__ __forceinline__ void gridbar(int* cnt, int target) {
    __syncthreads();
    if (threadIdx.x == 0) {
        __threadfence();   // release all prior global writes (agent scope)
        __hip_atomic_fetch_add(cnt, 1, __ATOMIC_ACQ_REL, __HIP_MEMORY_SCOPE_AGENT);
        while (__hip_atomic_load(cnt, __ATOMIC_ACQUIRE, __HIP_MEMORY_SCOPE_AGENT) < target)
            __builtin_amdgcn_s_sleep(2);
        __threadfence();   // acquire: invalidate stale caches before reads
    }
    __syncthreads();
}

// 256 persistent blocks x 512 threads. Phases:
//   1. hist  (24 role blocks): privatized LDS histograms -> part[24][NB]
//   2. scat  (24 role blocks): rederive scan from partials, rank+scatter
//   3. permz (all blocks, 2 tiles): z -> bf16 sorted rows zs[slot][C]
//   4. gather(all blocks, 2 groups of 32 queries): windowed MFMA decode
// Co-residency guaranteed: launch_bounds(512,2) caps VGPR<=256 -> 1 block/CU
// -> 256 blocks all resident on 256 CUs -> spin barriers cannot deadlock.
__global__ __launch_bounds__(TPB, 2) void mega_kernel(
    const float* __restrict__ xz, const float* __restrict__ z,
    const float* __restrict__ x,  const float* __restrict__ ls_p,
    int* __restrict__ cnt,        int* __restrict__ part,     // [24][NB]
    int* __restrict__ bst,        // [B][NB+1]
    float* __restrict__ xs,       int* __restrict__ islot,
    float* __restrict__ qcs,      int* __restrict__ qis,
    unsigned short* __restrict__ zs,   // [B*M + slack][C] bf16
    float* __restrict__ out)           // [B][N][C]
{
    __shared__ __align__(16) char smem[17472];   // phase-aliased arena
    const int t    = threadIdx.x;
    const int blk  = blockIdx.x;
    const int lane = t & 63;
    const int w    = t >> 6;

    // ---------------- phase 1: hist ----------------
    if (blk < 24) {
        int* h = (int*)smem;
        #pragma unroll
        for (int i = 0; i < 4; ++i) h[t + TPB * i] = 0;
        __syncthreads();
        const bool isQ = blk >= 16;
        const int  b   = isQ ? (blk - 16) >> 1 : blk >> 2;
        const int  sub = isQ ? (blk - 16) & 1  : blk & 3;
        const float* src = (isQ ? x + b * N : xz + b * M) + sub * 2048;
        float4 v4 = *(const float4*)(src + t * 4);
        atomicAdd(&h[bucket_of(v4.x)], 1);
        atomicAdd(&h[bucket_of(v4.y)], 1);
        atomicAdd(&h[bucket_of(v4.z)], 1);
        atomicAdd(&h[bucket_of(v4.w)], 1);
        __syncthreads();
        #pragma unroll
        for (int i = 0; i < 4; ++i) part[blk * NB + t + TPB * i] = h[t + TPB * i];
    }
    gridbar(cnt, GRID);

    // ---------------- phase 2: scat ----------------
    if (blk < 24) {
        int* base = (int*)smem;            // [2048]
        int* cl   = (int*)(smem + 8192);   // [2048]
        int* wsum = (int*)(smem + 16384);  // [8]
        const bool isQ = blk >= 16;
        const int  b   = isQ ? (blk - 16) >> 1 : blk >> 2;
        const int  sub = isQ ? (blk - 16) & 1  : blk & 3;
        const int  nsub = isQ ? NSUBQ : NSUBP;
        const int  pb0  = isQ ? 16 + b * 2 : b * 4;
        const float* src = (isQ ? x + b * N : xz + b * M) + sub * 2048;

        int tot[4], mine[4];
        #pragma unroll
        for (int j = 0; j < 4; ++j) { tot[j] = 0; mine[j] = 0; }
        for (int s_ = 0; s_ < nsub; ++s_) {
            #pragma unroll
            for (int j = 0; j < 4; ++j) {
                const int v = part[(pb0 + s_) * NB + t * 4 + j];
                tot[j] += v;
                if (s_ < sub) mine[j] += v;
            }
        }
        int pre[4]; int tsum = 0;
        #pragma unroll
        for (int j = 0; j < 4; ++j) { pre[j] = tsum; tsum += tot[j]; }
        int s = tsum;
        #pragma unroll
        for (int off = 1; off < 64; off <<= 1) {
            int up = __shfl_up(s, off, 64);
            if (lane >= off) s += up;
        }
        if (lane == 63) wsum[w] = s;
        #pragma unroll
        for (int i = 0; i < 4; ++i) cl[t + TPB * i] = 0;
        __syncthreads();
        int woff = 0;
        for (int i = 0; i < w; ++i) woff += wsum[i];
        const int excl = woff + s - tsum;          // excl start of bucket t*4
        #pragma unroll
        for (int j = 0; j < 4; ++j) base[t * 4 + j] = excl + pre[j] + mine[j];
        if (!isQ && sub == 0) {
            #pragma unroll
            for (int j = 0; j < 4; ++j)
                bst[b * (NB + 1) + t * 4 + j] = excl + pre[j];
            if (t == TPB - 1) bst[b * (NB + 1) + NB] = woff + s;   // == M
        }
        __syncthreads();
        float4 v4 = *(const float4*)(src + t * 4);
        float vv[4] = {v4.x, v4.y, v4.z, v4.w};
        #pragma unroll
        for (int c = 0; c < 4; ++c) {
            const int k    = bucket_of(vv[c]);
            const int slot = base[k] + atomicAdd(&cl[k], 1);
            const int orig = sub * 2048 + t * 4 + c;
            if (!isQ) {
                xs[b * M + slot]    = vv[c];
                islot[b * M + orig] = slot;
            } else {
                qcs[b * N + slot] = vv[c];
                qis[b * N + slot] = orig;
            }
        }
    }
    gridbar(cnt, 2 * GRID);

    // ---------------- phase 3: permz (2 tiles/block) ----------------
    {
        float (*tile)[65] = (float(*)[65])smem;     // 64 x 65 f32
        int* slot_s = (int*)(smem + 16640);         // [64]
        for (int h2 = 0; h2 < 2; ++h2) {
            const int tix = blk * 2 + h2;
            const int b   = tix >> 7;
            const int m0  = (tix & 127) * 64;
            __syncthreads();                        // tile/slot_s free
            const int m = t & 63;
            #pragma unroll
            for (int k = 0; k < 8; ++k) {
                int c = (t >> 6) + 8 * k;
                tile[c][m] = z[((size_t)b * C + c) * M + m0 + m];  // coalesced
            }
            if (t < 64) slot_s[t] = islot[b * M + m0 + t];
            __syncthreads();
            #pragma unroll
            for (int h3 = 0; h3 < 2; ++h3) {
                const int j  = (t >> 4) + 32 * h3;
                const int c4 = t & 15;
                ushort4 v4;
                v4.x = f2bf(tile[c4 * 4 + 0][j]);
                v4.y = f2bf(tile[c4 * 4 + 1][j]);
                v4.z = f2bf(tile[c4 * 4 + 2][j]);
                v4.w = f2bf(tile[c4 * 4 + 3][j]);
                ((ushort4*)zs)[((size_t)b * M + slot_s[j]) * 16 + c4] = v4;
            }
        }
    }
    gridbar(cnt, 3 * GRID);

    // ---------------- phase 4: gather (2 groups/block) ----------------
    {
        unsigned short* zr = (unsigned short*)smem;                    // [4096]
        unsigned short (*wl)[72] = (unsigned short(*)[72])(smem + 8192); // [32][72]
        float* qcS = (float*)(smem + 8192 + 4608);                     // [32]
        int*   qiS = (int*)(smem + 8192 + 4608 + 128);                 // [32]

        const float ls   = ls_p[0];
        const float coef = -0.5f * __expf(-2.0f * ls);   // negative
        const float R    = sqrtf(CUT / (-coef));
        const int quad = lane >> 4;
        const int low4 = lane & 15;
        const int qt   = w >> 2;            // query tile 0..1
        const int ct   = w & 3;             // channel tile 0..3
        const int qw   = w * 4 + quad;      // weight-phase query 0..31
        const int pg   = low4;              // weight-phase point group (x4)

        for (int h2 = 0; h2 < 2; ++h2) {
            const int g  = blk * 2 + h2;
            const int b  = g >> 7;          // 128 groups per batch
            const int g0 = (g & 127) * QG2;
            __syncthreads();                // zr/wl/qcS/qiS free
            if (t < QG2) {
                qcS[t] = qcs[b * N + g0 + t];
                qiS[t] = qis[b * N + g0 + t];
            }
            __syncthreads();
            float xmin = qcS[0], xmax = qcS[0];
            #pragma unroll
            for (int j = 1; j < QG2; ++j) {
                xmin = fminf(xmin, qcS[j]);
                xmax = fmaxf(xmax, qcS[j]);
            }
            const int s0 = bst[b * (NB + 1) + bucket_of(xmin - R)];
            const int s1 = bst[b * (NB + 1) + bucket_of(xmax + R) + 1];
            const int e0 = s0 & ~63;              // 64-aligned; M%64==0
            const int e1 = (s1 + 63) & ~63;
            const float qv = qcS[qw];
            f32x4 acc = {0.f, 0.f, 0.f, 0.f};
            const float* xsb = xs + b * M;
            const unsigned short* zsb = zs + (size_t)b * M * C;

            for (int cs = e0; cs < e1; cs += 64) {
                __syncthreads();                  // zr/wl free
                // stage 64 rows: 1 global_load_lds per wave (8 rows each)
                const unsigned short* gp =
                    zsb + ((size_t)cs + w * 8 + (lane >> 3)) * C + (lane & 7) * 8;
                __builtin_amdgcn_global_load_lds(
                    (const __attribute__((address_space(1))) void*)gp,
                    (__attribute__((address_space(3))) void*)(zr + w * 512),
                    16, 0, 0);
                // block-shared weights (overlap staging): 4 exp per lane
                const float4 xp4 = *(const float4*)(xsb + cs + pg * 4);
                float d0 = qv - xp4.x, d1 = qv - xp4.y;
                float d2 = qv - xp4.z, d3 = qv - xp4.w;
                ushort4 wv;
                wv.x = f2bf(__expf(coef * d0 * d0));
                wv.y = f2bf(__expf(coef * d1 * d1));
                wv.z = f2bf(__expf(coef * d2 * d2));
                wv.w = f2bf(__expf(coef * d3 * d3));
                *(ushort4*)&wl[qw][pg * 4] = wv;
                __syncthreads();                  // zr staged + wl written
                #pragma unroll
                for (int kh = 0; kh < 2; ++kh) {
                    short8 afrag = *(const short8*)&wl[qt * 16 + low4][kh * 32 + quad * 8];
                    short8 bfrag;
                    #pragma unroll
                    for (int j = 0; j < 8; ++j) {
                        const int p = kh * 32 + quad * 8 + j;
                        bfrag[j] = (short)zr[p * 64 + ct * 16 + low4];
                    }
                    acc = __builtin_amdgcn_mfma_f32_16x16x32_bf16(afrag, bfrag, acc, 0, 0, 0);
                }
            }
            // D: row(query within tile) = quad*4 + r, col = low4
            #pragma unroll
            for (int r = 0; r < 4; ++r) {
                const int q = qt * 16 + quad * 4 + r;
                out[((size_t)b * N + qiS[q]) * C + ct * 16 + low4] = acc[r];
            }
        }
    }
}

extern "C" void kernel_launch(void* const* d_in, const int* in_sizes, int n_in,
                              void* d_out, int out_size, void* d_ws, size_t ws_size,
                              hipStream_t stream) {
    const float* xz = (const float*)d_in[0];  // [B,M,1]
    const float* z  = (const float*)d_in[1];  // [B,C,M]
    const float* x  = (const float*)d_in[2];  // [B,N,1]
    const float* ls = (const float*)d_in[3];  // scalar
    float* out = (float*)d_out;               // [B,N,C]

    char* ws = (char*)d_ws;
    size_t off = 0;
    auto alloc = [&](size_t bytes) { void* p = ws + off; off += (bytes + 255) & ~size_t(255); return p; };

    int* cnt = (int*)alloc(256);                                                   // barrier counter
    unsigned short* zs = (unsigned short*)alloc(((size_t)B * M + 64) * C * sizeof(unsigned short));
    float* xs    = (float*)alloc(((size_t)B * M + 64) * sizeof(float));
    int*   islot = (int*)alloc((size_t)B * M * sizeof(int));
    float* qcs   = (float*)alloc((size_t)B * N * sizeof(float));
    int*   qis   = (int*)alloc((size_t)B * N * sizeof(int));
    int*   bst   = (int*)alloc((size_t)B * (NB + 1) * sizeof(int));
    int*   part  = (int*)alloc((size_t)24 * NB * sizeof(int));

    hipMemsetAsync(cnt, 0, sizeof(int), stream);
    mega_kernel<<<GRID, TPB, 0, stream>>>(xz, z, x, ls, cnt, part, bst,
                                          xs, islot, qcs, qis, zs, out);
}

// Round 7
// 84.033 us; speedup vs baseline: 2.2142x; 2.2142x over previous
//
#include <hip/hip_runtime.h>
#include <math.h>

#define B 4
#define N 4096
#define M 8192
#define C 64
#define NB 2048
#define XMIN (-64.0f)
#define INV_BW 16.0f   // bucket width 0.0625
#define CUT 10.0f      // truncation at exp(-10): err ~0.008 << 0.43
#define QG 16          // queries per group == MFMA M

typedef __attribute__((ext_vector_type(8))) short short8;   // 8 bf16
typedef __attribute__((ext_vector_type(4))) float f32x4;

__device__ __forceinline__ int bucket_of(float v) {
    int k = (int)floorf((v - XMIN) * INV_BW);
    return min(max(k, 0), NB - 1);
}

__device__ __forceinline__ unsigned short f2bf(float f) {   // RNE fp32->bf16
    unsigned int u = __float_as_uint(f);
    return (unsigned short)((u + 0x7FFF + ((u >> 16) & 1)) >> 16);
}

// Blocks 0..3: bin points (batch b) -> bucket_start, xs, islot.
// Blocks 4..7: bin queries (batch b) -> qcs/qis. Wave-shuffle scan.
__global__ __launch_bounds__(1024) void bin_kernel(
    const float* __restrict__ xz, const float* __restrict__ x,
    int* __restrict__ bucket_start,    // [B][NB+1]
    float* __restrict__ xs,            // [B*M + slack] sorted point coords
    int* __restrict__ islot,           // [B][M] original m -> sorted slot
    float* __restrict__ qcs,           // [B][N] sorted query coords
    int* __restrict__ qis)             // [B][N] sorted slot -> original n
{
    const int t    = threadIdx.x;
    const int lane = t & 63;
    const int w    = t >> 6;

    __shared__ int hist[NB];
    __shared__ int run[NB];
    __shared__ int wsum[16];
    const bool isQ = blockIdx.x >= 4;
    const int  b   = blockIdx.x & 3;
    const int  PT  = isQ ? (N / 1024) : (M / 1024);
    const float* src = isQ ? (x + b * N) : (xz + b * M);

    hist[t] = 0; hist[t + 1024] = 0;
    __syncthreads();

    float pv[8]; int pk[8];
    for (int j = 0; j < PT; ++j) {
        float v = src[j * 1024 + t];
        pv[j] = v; pk[j] = bucket_of(v);
        atomicAdd(&hist[pk[j]], 1);
    }
    __syncthreads();

    const int h0 = hist[2 * t], h1 = hist[2 * t + 1];
    const int tot = h0 + h1;
    int s = tot;
    #pragma unroll
    for (int off = 1; off < 64; off <<= 1) {
        int up = __shfl_up(s, off, 64);
        if (lane >= off) s += up;
    }
    if (lane == 63) wsum[w] = s;
    __syncthreads();
    int woff = 0;
    for (int i = 0; i < w; ++i) woff += wsum[i];
    const int excl = woff + s - tot;

    run[2 * t]     = excl;
    run[2 * t + 1] = excl + h0;
    if (!isQ) {
        bucket_start[b * (NB + 1) + 2 * t]     = excl;
        bucket_start[b * (NB + 1) + 2 * t + 1] = excl + h0;
        if (t == 1023) bucket_start[b * (NB + 1) + NB] = woff + s;  // == M
    }
    __syncthreads();

    if (!isQ) {
        for (int j = 0; j < PT; ++j) {
            int slot = atomicAdd(&run[pk[j]], 1);
            xs[b * M + slot]            = pv[j];
            islot[b * M + j * 1024 + t] = slot;
        }
    } else {
        for (int j = 0; j < PT; ++j) {
            int slot = atomicAdd(&run[pk[j]], 1);
            qcs[b * N + slot] = pv[j];
            qis[b * N + slot] = j * 1024 + t;
        }
    }
}

// 512 blocks: permute z [B,C,M] into bf16 sorted-row layout zs[slot][C].
__global__ __launch_bounds__(1024) void permz_kernel(
    const float* __restrict__ z, const int* __restrict__ islot,
    unsigned short* __restrict__ zs)   // [B*M + slack][C] bf16
{
    const int t  = threadIdx.x;
    const int b  = blockIdx.x >> 7;
    const int m0 = (blockIdx.x & 127) * 64;
    __shared__ float tile[64][65];
    __shared__ int slot_s[64];

    const int m = t & 63;
    #pragma unroll
    for (int k = 0; k < 4; ++k) {
        int c = (t >> 6) + 16 * k;
        tile[c][m] = z[((size_t)b * C + c) * M + m0 + m];   // coalesced in m
    }
    if (t < 64) slot_s[t] = islot[b * M + m0 + t];
    __syncthreads();

    const int j  = t >> 4;
    const int c4 = t & 15;
    ushort4 v4;
    v4.x = f2bf(tile[c4 * 4 + 0][j]);
    v4.y = f2bf(tile[c4 * 4 + 1][j]);
    v4.z = f2bf(tile[c4 * 4 + 2][j]);
    v4.w = f2bf(tile[c4 * 4 + 3][j]);
    ((ushort4*)zs)[((size_t)b * M + slot_s[j]) * 16 + c4] = v4;
}

// One block per 16 sorted queries; 4 waves; mfma_f32_16x16x32_bf16.
// Weights computed ONCE per block (4 exp/lane) into padded LDS wl;
// A-fragments = ds_read_b128 from wl; 64-aligned windows -> no masking
// (extra slots are real points with true weights; reference sums all M).
__global__ __launch_bounds__(256) void gather_kernel(
    const float* __restrict__ log_scale,
    const int* __restrict__ bucket_start,
    const float* __restrict__ xs,
    const float* __restrict__ qcs,
    const int* __restrict__ qis,
    const unsigned short* __restrict__ zs,   // [B*M + slack][C] bf16
    float* __restrict__ out)                 // [B][N][C]
{
    const int t    = threadIdx.x;
    const int lane = t & 63;
    const int w    = t >> 6;            // wave 0..3 -> channels w*16..+15
    const int quad = lane >> 4;         // 0..3
    const int low4 = lane & 15;
    const int g  = blockIdx.x;
    const int b  = g >> 8;              // 256 groups per batch
    const int g0 = (g & 255) * QG;

    __shared__ unsigned short zr[64 * 64];   // 8 KB: 64 rows x 64 ch bf16
    __shared__ unsigned short wl[QG][72];    // 2.25 KB padded (144B rows)
    __shared__ float qcS[QG];
    __shared__ int   qiS[QG];

    const float ls   = log_scale[0];
    const float coef = -0.5f * __expf(-2.0f * ls);   // negative
    const float R    = sqrtf(CUT / (-coef));

    if (t < QG) {
        qcS[t] = qcs[b * N + g0 + t];
        qiS[t] = qis[b * N + g0 + t];
    }
    __syncthreads();

    float xmin = qcS[0], xmax = qcS[0];
    #pragma unroll
    for (int j = 1; j < QG; ++j) {
        xmin = fminf(xmin, qcS[j]);
        xmax = fmaxf(xmax, qcS[j]);
    }
    const int s0 = bucket_start[b * (NB + 1) + bucket_of(xmin - R)];
    const int s1 = bucket_start[b * (NB + 1) + bucket_of(xmax + R) + 1];
    const int e0 = s0 & ~63;                 // 64-aligned window; M%64==0
    const int e1 = (s1 + 63) & ~63;          // so [e0,e1) stays in [0,M]

    // weight-phase mapping: this lane computes queries qw, points pg*4..+3
    const int qw = w * 4 + (lane >> 4);      // 0..15
    const int pg = lane & 15;                // point group (x4)
    const float qv = qcS[qw];

    f32x4 acc = {0.f, 0.f, 0.f, 0.f};

    const float* xsb = xs + b * M;
    const unsigned short* zsb = zs + (size_t)b * M * C;

    for (int cs = e0; cs < e1; cs += 64) {
        __syncthreads();                 // zr/wl free from previous chunk
        // stage rows cs..cs+63 (128B bf16 rows): 2 global_load_lds per wave
        #pragma unroll
        for (int r = 0; r < 2; ++r) {
            const unsigned short* gp =
                zsb + ((size_t)cs + (w * 2 + r) * 8 + (lane >> 3)) * C + (lane & 7) * 8;
            unsigned short* lp = zr + (w * 2 + r) * 512;   // wave-uniform base
            __builtin_amdgcn_global_load_lds(
                (const __attribute__((address_space(1))) void*)gp,
                (__attribute__((address_space(3))) void*)lp, 16, 0, 0);
        }
        // block-shared weights (overlap the staging): 4 exp per lane
        {
            const float4 xp4 = *(const float4*)(xsb + cs + pg * 4);  // 16B-aligned
            float d0 = qv - xp4.x, d1 = qv - xp4.y;
            float d2 = qv - xp4.z, d3 = qv - xp4.w;
            ushort4 wv;
            wv.x = f2bf(__expf(coef * d0 * d0));
            wv.y = f2bf(__expf(coef * d1 * d1));
            wv.z = f2bf(__expf(coef * d2 * d2));
            wv.w = f2bf(__expf(coef * d3 * d3));
            *(ushort4*)&wl[qw][pg * 4] = wv;
        }
        __syncthreads();                 // zr staged + wl written
        // A = weights via b128 (padded rows), B = zr scalar u16, 2 MFMA
        #pragma unroll
        for (int kh = 0; kh < 2; ++kh) {
            short8 afrag = *(const short8*)&wl[low4][kh * 32 + quad * 8];
            short8 bfrag;
            #pragma unroll
            for (int j = 0; j < 8; ++j) {
                const int p = kh * 32 + quad * 8 + j;
                bfrag[j] = (short)zr[p * 64 + w * 16 + low4];
            }
            acc = __builtin_amdgcn_mfma_f32_16x16x32_bf16(afrag, bfrag, acc, 0, 0, 0);
        }
    }

    // D: row(query) = quad*4 + r, col(channel local) = low4
    #pragma unroll
    for (int r = 0; r < 4; ++r) {
        const int q = quad * 4 + r;
        out[((size_t)b * N + qiS[q]) * C + w * 16 + low4] = acc[r];
    }
}

extern "C" void kernel_launch(void* const* d_in, const int* in_sizes, int n_in,
                              void* d_out, int out_size, void* d_ws, size_t ws_size,
                              hipStream_t stream) {
    const float* xz = (const float*)d_in[0];  // [B,M,1]
    const float* z  = (const float*)d_in[1];  // [B,C,M]
    const float* x  = (const float*)d_in[2];  // [B,N,1]
    const float* ls = (const float*)d_in[3];  // scalar
    float* out = (float*)d_out;               // [B,N,C]

    char* ws = (char*)d_ws;
    size_t off = 0;
    auto alloc = [&](size_t bytes) { void* p = ws + off; off += (bytes + 255) & ~size_t(255); return p; };

    unsigned short* zs = (unsigned short*)alloc(((size_t)B * M + 64) * C * sizeof(unsigned short)); // ~4.2MB
    float* xs    = (float*)alloc(((size_t)B * M + 64) * sizeof(float));
    int*   islot = (int*)alloc((size_t)B * M * sizeof(int));
    float* qcs   = (float*)alloc((size_t)B * N * sizeof(float));
    int*   qis   = (int*)alloc((size_t)B * N * sizeof(int));
    int*   bst   = (int*)alloc((size_t)B * (NB + 1) * sizeof(int));

    bin_kernel<<<8, 1024, 0, stream>>>(xz, x, bst, xs, islot, qcs, qis);
    permz_kernel<<<512, 1024, 0, stream>>>(z, islot, zs);
    gather_kernel<<<B * (N / QG), 256, 0, stream>>>(ls, bst, xs, qcs, qis, zs, out);
}

// Round 8
// 82.445 us; speedup vs baseline: 2.2568x; 1.0193x over previous
//
#include <hip/hip_runtime.h>
#include <math.h>

#define B 4
#define N 4096
#define M 8192
#define C 64
#define NB 2048
#define XMIN (-64.0f)
#define INV_BW 16.0f   // bucket width 0.0625
#define CUT 10.0f      // truncation at exp(-10): err ~0.008 << tolerance
#define QG 16          // queries per group == MFMA M
#define NSUBP 4        // point sub-blocks per batch (2048 elems each)
#define NSUBQ 2        // query sub-blocks per batch (2048 elems each)

typedef __attribute__((ext_vector_type(8))) short short8;   // 8 bf16
typedef __attribute__((ext_vector_type(4))) float f32x4;

__device__ __forceinline__ int bucket_of(float v) {
    int k = (int)floorf((v - XMIN) * INV_BW);
    return min(max(k, 0), NB - 1);
}

__device__ __forceinline__ unsigned short f2bf(float f) {   // RNE fp32->bf16
    unsigned int u = __float_as_uint(f);
    return (unsigned short)((u + 0x7FFF + ((u >> 16) & 1)) >> 16);
}

// K1: blocks 0..23 = privatized LDS histograms over 2048-elem sub-ranges
//     (r3-verified logic; part[24][NB] fully written -> no zeroing race).
//     blocks 24..535 = pure transpose+cast z [B,C,M] -> zt[b][m][C] bf16 in
//     ORIGINAL m order (independent of the sort -> overlaps the histogram;
//     both sides fully coalesced).
__global__ __launch_bounds__(1024) void prep_kernel(
    const float* __restrict__ xz, const float* __restrict__ x,
    const float* __restrict__ z,
    int* __restrict__ part,            // [24][NB]
    unsigned short* __restrict__ zt)   // [B*M][C] bf16, original order
{
    const int t   = threadIdx.x;
    const int blk = blockIdx.x;

    __shared__ int   h[NB];            // hist branch
    __shared__ float tile[64][65];     // transpose branch (separate alloc ok)

    if (blk < 24) {
        h[t] = 0; h[t + 1024] = 0;
        __syncthreads();
        const bool isQ = blk >= 16;
        const int  b   = isQ ? (blk - 16) >> 1 : blk >> 2;
        const int  sub = isQ ? (blk - 16) & 1  : blk & 3;
        const float* src = (isQ ? x + b * N : xz + b * M) + sub * 2048;
        float2 v2 = *(const float2*)(src + t * 2);
        atomicAdd(&h[bucket_of(v2.x)], 1);
        atomicAdd(&h[bucket_of(v2.y)], 1);
        __syncthreads();
        part[blk * NB + t]        = h[t];
        part[blk * NB + 1024 + t] = h[1024 + t];
    } else {
        const int tix = blk - 24;          // 0..511
        const int b   = tix >> 7;
        const int m0  = (tix & 127) * 64;
        const int m   = t & 63;
        #pragma unroll
        for (int k = 0; k < 4; ++k) {
            int c = (t >> 6) + 16 * k;
            tile[c][m] = z[((size_t)b * C + c) * M + m0 + m];   // coalesced in m
        }
        __syncthreads();
        const int j  = t >> 4;             // row (point) 0..63
        const int c4 = t & 15;
        ushort4 v4;
        v4.x = f2bf(tile[c4 * 4 + 0][j]);
        v4.y = f2bf(tile[c4 * 4 + 1][j]);
        v4.z = f2bf(tile[c4 * 4 + 2][j]);
        v4.w = f2bf(tile[c4 * 4 + 3][j]);
        ((ushort4*)zt)[((size_t)b * M + m0 + j) * 16 + c4] = v4;  // coalesced
    }
}

// K2: 24 blocks x 256 (r3-verified): each block re-derives the full
// per-(b,kind) bucket scan from the partials, adds prior-sub offsets, then
// ranks its own 2048 elements with block-local LDS atomics. Slot ranges
// across blocks disjoint by construction -> no inter-block atomics.
// Emits iord[slot] = original index (slot->m), r1-verified direction.
__global__ __launch_bounds__(256) void scat_kernel(
    const float* __restrict__ xz, const float* __restrict__ x,
    const int* __restrict__ part,      // [24][NB]
    int* __restrict__ bucket_start,    // [B][NB+1]
    float* __restrict__ xs,            // [B*M] sorted point coords
    int* __restrict__ iord,            // [B][M] sorted slot -> original m
    float* __restrict__ qcs,           // [B][N] sorted query coords
    int* __restrict__ qis)             // [B][N] sorted slot -> original n
{
    const int t    = threadIdx.x;
    const int lane = t & 63;
    const int w    = t >> 6;
    const int bid  = blockIdx.x;
    const bool isQ = bid >= 16;
    const int  b   = isQ ? (bid - 16) >> 1 : bid >> 2;
    const int  sub = isQ ? (bid - 16) & 1  : bid & 3;
    const int  nsub = isQ ? NSUBQ : NSUBP;
    const int  pb0  = isQ ? 16 + b * 2 : b * 4;
    const float* src = (isQ ? x + b * N : xz + b * M) + sub * 2048;

    __shared__ int base[NB];
    __shared__ int cnt[NB];
    __shared__ int wsum[4];

    // per-thread 8 contiguous buckets: totals + prior-sub ("mine") counts
    int tot[8], mine[8];
    #pragma unroll
    for (int j = 0; j < 8; ++j) { tot[j] = 0; mine[j] = 0; }
    for (int s_ = 0; s_ < nsub; ++s_) {
        #pragma unroll
        for (int j = 0; j < 8; ++j) {
            const int v = part[(pb0 + s_) * NB + t * 8 + j];
            tot[j] += v;
            if (s_ < sub) mine[j] += v;
        }
    }
    int pre[8]; int tsum = 0;
    #pragma unroll
    for (int j = 0; j < 8; ++j) { pre[j] = tsum; tsum += tot[j]; }
    int s = tsum;
    #pragma unroll
    for (int off = 1; off < 64; off <<= 1) {
        int up = __shfl_up(s, off, 64);
        if (lane >= off) s += up;
    }
    if (lane == 63) wsum[w] = s;
    #pragma unroll
    for (int i = 0; i < 8; ++i) cnt[t + 256 * i] = 0;
    __syncthreads();
    int woff = 0;
    for (int i = 0; i < w; ++i) woff += wsum[i];
    const int excl = woff + s - tsum;            // exclusive start of bucket t*8
    #pragma unroll
    for (int j = 0; j < 8; ++j) base[t * 8 + j] = excl + pre[j] + mine[j];
    if (!isQ && sub == 0) {
        #pragma unroll
        for (int j = 0; j < 8; ++j)
            bucket_start[b * (NB + 1) + t * 8 + j] = excl + pre[j];
        if (t == 255) bucket_start[b * (NB + 1) + NB] = woff + s;   // == M
    }
    __syncthreads();

    #pragma unroll
    for (int j = 0; j < 2; ++j) {
        float4 v4 = *(const float4*)(src + t * 4 + j * 1024);
        float vv[4] = {v4.x, v4.y, v4.z, v4.w};
        #pragma unroll
        for (int c = 0; c < 4; ++c) {
            const int k    = bucket_of(vv[c]);
            const int slot = base[k] + atomicAdd(&cnt[k], 1);
            const int orig = sub * 2048 + t * 4 + j * 1024 + c;
            if (!isQ) {
                xs[b * M + slot]   = vv[c];
                iord[b * M + slot] = orig;
            } else {
                qcs[b * N + slot] = vv[c];
                qis[b * N + slot] = orig;
            }
        }
    }
}

// K3: one block per 16 sorted queries; 4 waves; mfma_f32_16x16x32_bf16.
// r0-verified core; staging now INDIRECT: lane reads gm = iord[cs+row]
// (8-lane-uniform) and stages the contiguous 128B row zt[gm][.] via
// per-lane-source global_load_lds (LDS dest stays linear -> same zr layout,
// same MFMA fragments, bit-identical output).
__global__ __launch_bounds__(256) void gather_kernel(
    const float* __restrict__ log_scale,
    const int* __restrict__ bucket_start,
    const float* __restrict__ xs,
    const float* __restrict__ qcs,
    const int* __restrict__ qis,
    const int* __restrict__ iord,            // [B][M] slot -> m
    const unsigned short* __restrict__ zt,   // [B*M][C] bf16 original order
    float* __restrict__ out)                 // [B][N][C]
{
    const int t    = threadIdx.x;
    const int lane = t & 63;
    const int w    = t >> 6;            // wave 0..3 -> channels w*16..+15
    const int quad = lane >> 4;         // 0..3
    const int low4 = lane & 15;
    const int g  = blockIdx.x;
    const int b  = g >> 8;              // 256 groups per batch
    const int g0 = (g & 255) * QG;

    __shared__ unsigned short zr[64 * 64];   // 8 KB: 64 rows x 64 ch bf16
    __shared__ unsigned short wl[QG][72];    // 2.25 KB padded (144B rows)
    __shared__ float qcS[QG];
    __shared__ int   qiS[QG];

    const float ls   = log_scale[0];
    const float coef = -0.5f * __expf(-2.0f * ls);   // negative
    const float R    = sqrtf(CUT / (-coef));

    if (t < QG) {
        qcS[t] = qcs[b * N + g0 + t];
        qiS[t] = qis[b * N + g0 + t];
    }
    __syncthreads();

    float xmin = qcS[0], xmax = qcS[0];
    #pragma unroll
    for (int j = 1; j < QG; ++j) {
        xmin = fminf(xmin, qcS[j]);
        xmax = fmaxf(xmax, qcS[j]);
    }
    const int s0 = bucket_start[b * (NB + 1) + bucket_of(xmin - R)];
    const int s1 = bucket_start[b * (NB + 1) + bucket_of(xmax + R) + 1];
    const int e0 = s0 & ~63;                 // 64-aligned window; M%64==0
    const int e1 = (s1 + 63) & ~63;          // so [e0,e1) stays in [0,M]

    // weight-phase mapping: this lane computes queries qw, points pg*4..+3
    const int qw = w * 4 + (lane >> 4);      // 0..15
    const int pg = lane & 15;                // point group (x4)
    const float qv = qcS[qw];

    f32x4 acc = {0.f, 0.f, 0.f, 0.f};

    const float* xsb = xs + b * M;
    const int* iordb = iord + b * M;
    const unsigned short* ztb = zt + (size_t)b * M * C;

    for (int cs = e0; cs < e1; cs += 64) {
        __syncthreads();                 // zr/wl free from previous chunk
        // stage rows cs..cs+63: indirect 128B rows, 2 global_load_lds/wave
        #pragma unroll
        for (int r = 0; r < 2; ++r) {
            const int ridx = (w * 2 + r) * 8 + (lane >> 3);
            const int gm   = iordb[cs + ridx];          // 8-lane-uniform
            const unsigned short* gp = ztb + (size_t)gm * C + (lane & 7) * 8;
            unsigned short* lp = zr + (w * 2 + r) * 512;   // wave-uniform base
            __builtin_amdgcn_global_load_lds(
                (const __attribute__((address_space(1))) void*)gp,
                (__attribute__((address_space(3))) void*)lp, 16, 0, 0);
        }
        // block-shared weights (overlap the staging): 4 exp per lane
        {
            const float4 xp4 = *(const float4*)(xsb + cs + pg * 4);  // 16B-aligned
            float d0 = qv - xp4.x, d1 = qv - xp4.y;
            float d2 = qv - xp4.z, d3 = qv - xp4.w;
            ushort4 wv;
            wv.x = f2bf(__expf(coef * d0 * d0));
            wv.y = f2bf(__expf(coef * d1 * d1));
            wv.z = f2bf(__expf(coef * d2 * d2));
            wv.w = f2bf(__expf(coef * d3 * d3));
            *(ushort4*)&wl[qw][pg * 4] = wv;
        }
        __syncthreads();                 // zr staged + wl written
        // A = weights via b128 (padded rows), B = zr scalar u16, 2 MFMA
        #pragma unroll
        for (int kh = 0; kh < 2; ++kh) {
            short8 afrag = *(const short8*)&wl[low4][kh * 32 + quad * 8];
            short8 bfrag;
            #pragma unroll
            for (int j = 0; j < 8; ++j) {
                const int p = kh * 32 + quad * 8 + j;
                bfrag[j] = (short)zr[p * 64 + w * 16 + low4];
            }
            acc = __builtin_amdgcn_mfma_f32_16x16x32_bf16(afrag, bfrag, acc, 0, 0, 0);
        }
    }

    // D: row(query) = quad*4 + r, col(channel local) = low4
    #pragma unroll
    for (int r = 0; r < 4; ++r) {
        const int q = quad * 4 + r;
        out[((size_t)b * N + qiS[q]) * C + w * 16 + low4] = acc[r];
    }
}

extern "C" void kernel_launch(void* const* d_in, const int* in_sizes, int n_in,
                              void* d_out, int out_size, void* d_ws, size_t ws_size,
                              hipStream_t stream) {
    const float* xz = (const float*)d_in[0];  // [B,M,1]
    const float* z  = (const float*)d_in[1];  // [B,C,M]
    const float* x  = (const float*)d_in[2];  // [B,N,1]
    const float* ls = (const float*)d_in[3];  // scalar
    float* out = (float*)d_out;               // [B,N,C]

    char* ws = (char*)d_ws;
    size_t off = 0;
    auto alloc = [&](size_t bytes) { void* p = ws + off; off += (bytes + 255) & ~size_t(255); return p; };

    unsigned short* zt = (unsigned short*)alloc((size_t)B * M * C * sizeof(unsigned short)); // 4MB
    float* xs   = (float*)alloc(((size_t)B * M + 64) * sizeof(float));
    int*   iord = (int*)alloc((size_t)B * M * sizeof(int));
    float* qcs  = (float*)alloc((size_t)B * N * sizeof(float));
    int*   qis  = (int*)alloc((size_t)B * N * sizeof(int));
    int*   bst  = (int*)alloc((size_t)B * (NB + 1) * sizeof(int));
    int*   part = (int*)alloc((size_t)24 * NB * sizeof(int));

    prep_kernel<<<536, 1024, 0, stream>>>(xz, x, z, part, zt);
    scat_kernel<<<24, 256, 0, stream>>>(xz, x, part, bst, xs, iord, qcs, qis);
    gather_kernel<<<B * (N / QG), 256, 0, stream>>>(ls, bst, xs, qcs, qis, iord, zt, out);
}

// Round 9
// 81.965 us; speedup vs baseline: 2.2701x; 1.0059x over previous
//
#include <hip/hip_runtime.h>
#include <math.h>

#define B 4
#define N 4096
#define M 8192
#define C 64
#define NB 2048
#define XMIN (-64.0f)
#define INV_BW 16.0f   // bucket width 0.0625
#define CUT 10.0f      // truncation at exp(-10): err ~0.008 << tolerance
#define QG 16          // queries per group == MFMA M
#define NSUBP 4        // point sub-blocks per batch (2048 elems each)
#define NSUBQ 2        // query sub-blocks per batch (2048 elems each)

typedef __attribute__((ext_vector_type(8))) short short8;   // 8 bf16
typedef __attribute__((ext_vector_type(4))) float f32x4;

__device__ __forceinline__ int bucket_of(float v) {
    int k = (int)floorf((v - XMIN) * INV_BW);
    return min(max(k, 0), NB - 1);
}

__device__ __forceinline__ unsigned short f2bf(float f) {   // RNE fp32->bf16
    unsigned int u = __float_as_uint(f);
    return (unsigned short)((u + 0x7FFF + ((u >> 16) & 1)) >> 16);
}

// K1: blocks 0..23 = privatized LDS histograms over 2048-elem sub-ranges
//     (r3/r8-verified logic; part[24][NB] fully written -> no zeroing race).
//     blocks 24..535 = pure transpose+cast z [B,C,M] -> zt[b][m][C] bf16 in
//     ORIGINAL m order (independent of the sort -> overlaps the histogram;
//     both sides fully coalesced).
__global__ __launch_bounds__(1024) void prep_kernel(
    const float* __restrict__ xz, const float* __restrict__ x,
    const float* __restrict__ z,
    int* __restrict__ part,            // [24][NB]
    unsigned short* __restrict__ zt)   // [B*M][C] bf16, original order
{
    const int t   = threadIdx.x;
    const int blk = blockIdx.x;

    __shared__ int   h[NB];            // hist branch
    __shared__ float tile[64][65];     // transpose branch

    if (blk < 24) {
        h[t] = 0; h[t + 1024] = 0;
        __syncthreads();
        const bool isQ = blk >= 16;
        const int  b   = isQ ? (blk - 16) >> 1 : blk >> 2;
        const int  sub = isQ ? (blk - 16) & 1  : blk & 3;
        const float* src = (isQ ? x + b * N : xz + b * M) + sub * 2048;
        float2 v2 = *(const float2*)(src + t * 2);
        atomicAdd(&h[bucket_of(v2.x)], 1);
        atomicAdd(&h[bucket_of(v2.y)], 1);
        __syncthreads();
        part[blk * NB + t]        = h[t];
        part[blk * NB + 1024 + t] = h[1024 + t];
    } else {
        const int tix = blk - 24;          // 0..511
        const int b   = tix >> 7;
        const int m0  = (tix & 127) * 64;
        const int m   = t & 63;
        #pragma unroll
        for (int k = 0; k < 4; ++k) {
            int c = (t >> 6) + 16 * k;
            tile[c][m] = z[((size_t)b * C + c) * M + m0 + m];   // coalesced in m
        }
        __syncthreads();
        const int j  = t >> 4;             // row (point) 0..63
        const int c4 = t & 15;
        ushort4 v4;
        v4.x = f2bf(tile[c4 * 4 + 0][j]);
        v4.y = f2bf(tile[c4 * 4 + 1][j]);
        v4.z = f2bf(tile[c4 * 4 + 2][j]);
        v4.w = f2bf(tile[c4 * 4 + 3][j]);
        ((ushort4*)zt)[((size_t)b * M + m0 + j) * 16 + c4] = v4;  // coalesced
    }
}

// K2: 24 blocks x 256 (r3/r8-verified): each block re-derives the full
// per-(b,kind) bucket scan from the partials, adds prior-sub offsets, then
// ranks its own 2048 elements with block-local LDS atomics. Slot ranges
// across blocks disjoint by construction -> no inter-block atomics.
// Emits iord[slot] = original index (slot->m).
__global__ __launch_bounds__(256) void scat_kernel(
    const float* __restrict__ xz, const float* __restrict__ x,
    const int* __restrict__ part,      // [24][NB]
    int* __restrict__ bucket_start,    // [B][NB+1]
    float* __restrict__ xs,            // [B*M] sorted point coords
    int* __restrict__ iord,            // [B][M] sorted slot -> original m
    float* __restrict__ qcs,           // [B][N] sorted query coords
    int* __restrict__ qis)             // [B][N] sorted slot -> original n
{
    const int t    = threadIdx.x;
    const int lane = t & 63;
    const int w    = t >> 6;
    const int bid  = blockIdx.x;
    const bool isQ = bid >= 16;
    const int  b   = isQ ? (bid - 16) >> 1 : bid >> 2;
    const int  sub = isQ ? (bid - 16) & 1  : bid & 3;
    const int  nsub = isQ ? NSUBQ : NSUBP;
    const int  pb0  = isQ ? 16 + b * 2 : b * 4;
    const float* src = (isQ ? x + b * N : xz + b * M) + sub * 2048;

    __shared__ int base[NB];
    __shared__ int cnt[NB];
    __shared__ int wsum[4];

    int tot[8], mine[8];
    #pragma unroll
    for (int j = 0; j < 8; ++j) { tot[j] = 0; mine[j] = 0; }
    for (int s_ = 0; s_ < nsub; ++s_) {
        #pragma unroll
        for (int j = 0; j < 8; ++j) {
            const int v = part[(pb0 + s_) * NB + t * 8 + j];
            tot[j] += v;
            if (s_ < sub) mine[j] += v;
        }
    }
    int pre[8]; int tsum = 0;
    #pragma unroll
    for (int j = 0; j < 8; ++j) { pre[j] = tsum; tsum += tot[j]; }
    int s = tsum;
    #pragma unroll
    for (int off = 1; off < 64; off <<= 1) {
        int up = __shfl_up(s, off, 64);
        if (lane >= off) s += up;
    }
    if (lane == 63) wsum[w] = s;
    #pragma unroll
    for (int i = 0; i < 8; ++i) cnt[t + 256 * i] = 0;
    __syncthreads();
    int woff = 0;
    for (int i = 0; i < w; ++i) woff += wsum[i];
    const int excl = woff + s - tsum;            // exclusive start of bucket t*8
    #pragma unroll
    for (int j = 0; j < 8; ++j) base[t * 8 + j] = excl + pre[j] + mine[j];
    if (!isQ && sub == 0) {
        #pragma unroll
        for (int j = 0; j < 8; ++j)
            bucket_start[b * (NB + 1) + t * 8 + j] = excl + pre[j];
        if (t == 255) bucket_start[b * (NB + 1) + NB] = woff + s;   // == M
    }
    __syncthreads();

    #pragma unroll
    for (int j = 0; j < 2; ++j) {
        float4 v4 = *(const float4*)(src + t * 4 + j * 1024);
        float vv[4] = {v4.x, v4.y, v4.z, v4.w};
        #pragma unroll
        for (int c = 0; c < 4; ++c) {
            const int k    = bucket_of(vv[c]);
            const int slot = base[k] + atomicAdd(&cnt[k], 1);
            const int orig = sub * 2048 + t * 4 + j * 1024 + c;
            if (!isQ) {
                xs[b * M + slot]   = vv[c];
                iord[b * M + slot] = orig;
            } else {
                qcs[b * N + slot] = vv[c];
                qis[b * N + slot] = orig;
            }
        }
    }
}

// K3: one block per 16 sorted queries; 4 waves; mfma_f32_16x16x32_bf16.
// r8-verified core with two latency-chain cuts:
//  (a) scalar window calc: slots are bucket-sorted, so the group min/max lie
//      in the same buckets as qcs[g0]/qcs[g0+15]; widen +-1 bucket -> strict
//      SUPERSET window (extra points carry true tiny weights). Uniform
//      s_load path, no LDS fmin chain, no sync dependency.
//  (b) iord/xs prefetch: chunk i+1's indirection + coords loaded during
//      chunk i's weight/MFMA phase.
__global__ __launch_bounds__(256) void gather_kernel(
    const float* __restrict__ log_scale,
    const int* __restrict__ bucket_start,
    const float* __restrict__ xs,
    const float* __restrict__ qcs,
    const int* __restrict__ qis,
    const int* __restrict__ iord,            // [B][M] slot -> m
    const unsigned short* __restrict__ zt,   // [B*M][C] bf16 original order
    float* __restrict__ out)                 // [B][N][C]
{
    const int t    = threadIdx.x;
    const int lane = t & 63;
    const int w    = t >> 6;            // wave 0..3 -> channels w*16..+15
    const int quad = lane >> 4;         // 0..3
    const int low4 = lane & 15;
    const int g  = blockIdx.x;
    const int b  = g >> 8;              // 256 groups per batch
    const int g0 = (g & 255) * QG;

    __shared__ unsigned short zr[64 * 64];   // 8 KB: 64 rows x 64 ch bf16
    __shared__ unsigned short wl[QG][72];    // 2.25 KB padded (144B rows)
    __shared__ float qcS[QG];
    __shared__ int   qiS[QG];

    const float ls   = log_scale[0];
    const float coef = -0.5f * __expf(-2.0f * ls);   // negative
    const float R    = sqrtf(CUT / (-coef));

    if (t < QG) {
        qcS[t] = qcs[b * N + g0 + t];
        qiS[t] = qis[b * N + g0 + t];
    }

    // (a) scalar superset window — overlaps the qcS/qiS staging above
    const float qlo = qcs[b * N + g0];
    const float qhi = qcs[b * N + g0 + QG - 1];
    const int k0 = max(bucket_of(qlo - R) - 1, 0);
    const int k1 = min(bucket_of(qhi + R) + 1, NB - 1);
    const int s0 = bucket_start[b * (NB + 1) + k0];
    const int s1 = bucket_start[b * (NB + 1) + k1 + 1];
    const int e0 = s0 & ~63;                 // 64-aligned window; M%64==0
    const int e1 = (s1 + 63) & ~63;          // so [e0,e1) stays in [0,M]

    // weight-phase mapping: this lane computes queries qw, points pg*4..+3
    const int qw = w * 4 + quad;             // 0..15
    const int pg = low4;                     // point group (x4)

    const float* xsb = xs + b * M;
    const int* iordb = iord + b * M;
    const unsigned short* ztb = zt + (size_t)b * M * C;

    // (b) prefetch chunk 0's indirection + coords
    const int ridx0 = (w * 2 + 0) * 8 + (lane >> 3);
    const int ridx1 = (w * 2 + 1) * 8 + (lane >> 3);
    int gmA = 0, gmB = 0;
    float4 xpA = {0.f, 0.f, 0.f, 0.f};
    if (e0 < e1) {
        gmA = iordb[e0 + ridx0];
        gmB = iordb[e0 + ridx1];
        xpA = *(const float4*)(xsb + e0 + pg * 4);
    }

    __syncthreads();                         // qcS/qiS staged
    const float qv = qcS[qw];

    f32x4 acc = {0.f, 0.f, 0.f, 0.f};

    for (int cs = e0; cs < e1; cs += 64) {
        __syncthreads();                 // zr/wl free from previous chunk
        // stage rows cs..cs+63: indirect 128B rows, 2 global_load_lds/wave
        {
            const unsigned short* gpA = ztb + (size_t)gmA * C + (lane & 7) * 8;
            const unsigned short* gpB = ztb + (size_t)gmB * C + (lane & 7) * 8;
            __builtin_amdgcn_global_load_lds(
                (const __attribute__((address_space(1))) void*)gpA,
                (__attribute__((address_space(3))) void*)(zr + (w * 2 + 0) * 512),
                16, 0, 0);
            __builtin_amdgcn_global_load_lds(
                (const __attribute__((address_space(1))) void*)gpB,
                (__attribute__((address_space(3))) void*)(zr + (w * 2 + 1) * 512),
                16, 0, 0);
        }
        // weights for THIS chunk from prefetched xpA (overlap the staging)
        {
            float d0 = qv - xpA.x, d1 = qv - xpA.y;
            float d2 = qv - xpA.z, d3 = qv - xpA.w;
            ushort4 wv;
            wv.x = f2bf(__expf(coef * d0 * d0));
            wv.y = f2bf(__expf(coef * d1 * d1));
            wv.z = f2bf(__expf(coef * d2 * d2));
            wv.w = f2bf(__expf(coef * d3 * d3));
            *(ushort4*)&wl[qw][pg * 4] = wv;
        }
        // prefetch chunk i+1's iord/xs (hides L2/L3 latency under MFMA)
        if (cs + 64 < e1) {
            gmA = iordb[cs + 64 + ridx0];
            gmB = iordb[cs + 64 + ridx1];
            xpA = *(const float4*)(xsb + cs + 64 + pg * 4);
        }
        __syncthreads();                 // zr staged + wl written
        // A = weights via b128 (padded rows), B = zr scalar u16, 2 MFMA
        #pragma unroll
        for (int kh = 0; kh < 2; ++kh) {
            short8 afrag = *(const short8*)&wl[low4][kh * 32 + quad * 8];
            short8 bfrag;
            #pragma unroll
            for (int j = 0; j < 8; ++j) {
                const int p = kh * 32 + quad * 8 + j;
                bfrag[j] = (short)zr[p * 64 + w * 16 + low4];
            }
            acc = __builtin_amdgcn_mfma_f32_16x16x32_bf16(afrag, bfrag, acc, 0, 0, 0);
        }
    }

    // D: row(query) = quad*4 + r, col(channel local) = low4
    #pragma unroll
    for (int r = 0; r < 4; ++r) {
        const int q = quad * 4 + r;
        out[((size_t)b * N + qiS[q]) * C + w * 16 + low4] = acc[r];
    }
}

extern "C" void kernel_launch(void* const* d_in, const int* in_sizes, int n_in,
                              void* d_out, int out_size, void* d_ws, size_t ws_size,
                              hipStream_t stream) {
    const float* xz = (const float*)d_in[0];  // [B,M,1]
    const float* z  = (const float*)d_in[1];  // [B,C,M]
    const float* x  = (const float*)d_in[2];  // [B,N,1]
    const float* ls = (const float*)d_in[3];  // scalar
    float* out = (float*)d_out;               // [B,N,C]

    char* ws = (char*)d_ws;
    size_t off = 0;
    auto alloc = [&](size_t bytes) { void* p = ws + off; off += (bytes + 255) & ~size_t(255); return p; };

    unsigned short* zt = (unsigned short*)alloc((size_t)B * M * C * sizeof(unsigned short)); // 4MB
    float* xs   = (float*)alloc(((size_t)B * M + 64) * sizeof(float));
    int*   iord = (int*)alloc((size_t)B * M * sizeof(int));
    float* qcs  = (float*)alloc((size_t)B * N * sizeof(float));
    int*   qis  = (int*)alloc((size_t)B * N * sizeof(int));
    int*   bst  = (int*)alloc((size_t)B * (NB + 1) * sizeof(int));
    int*   part = (int*)alloc((size_t)24 * NB * sizeof(int));

    prep_kernel<<<536, 1024, 0, stream>>>(xz, x, z, part, zt);
    scat_kernel<<<24, 256, 0, stream>>>(xz, x, part, bst, xs, iord, qcs, qis);
    gather_kernel<<<B * (N / QG), 256, 0, stream>>>(ls, bst, xs, qcs, qis, iord, zt, out);
}

// Round 10
// 81.750 us; speedup vs baseline: 2.2760x; 1.0026x over previous
//
#include <hip/hip_runtime.h>
#include <math.h>

#define B 4
#define N 4096
#define M 8192
#define C 64
#define NB 2048
#define XMIN (-64.0f)
#define INV_BW 16.0f   // bucket width 0.0625
#define CUT 10.0f      // truncation at exp(-10): err ~0.008 << tolerance
#define QG 16          // queries per group == MFMA M
#define NSUBP 4        // point sub-blocks per batch (2048 elems each)
#define NSUBQ 2        // query sub-blocks per batch (2048 elems each)

typedef __attribute__((ext_vector_type(8))) short short8;   // 8 bf16
typedef __attribute__((ext_vector_type(4))) float f32x4;

__device__ __forceinline__ int bucket_of(float v) {
    int k = (int)floorf((v - XMIN) * INV_BW);
    return min(max(k, 0), NB - 1);
}

__device__ __forceinline__ unsigned short f2bf(float f) {   // RNE fp32->bf16
    unsigned int u = __float_as_uint(f);
    return (unsigned short)((u + 0x7FFF + ((u >> 16) & 1)) >> 16);
}

// K1: 24 blocks x 1024 — privatized LDS histograms over 2048-elem sub-ranges
// (r9-verified branch, now standalone so K2's scat can overlap the transpose).
// part[24][NB] fully written -> no zeroing race, no global atomics.
__global__ __launch_bounds__(1024) void hist_kernel(
    const float* __restrict__ xz, const float* __restrict__ x,
    int* __restrict__ part)            // [24][NB]
{
    const int t   = threadIdx.x;
    const int blk = blockIdx.x;
    __shared__ int h[NB];
    h[t] = 0; h[t + 1024] = 0;
    __syncthreads();
    const bool isQ = blk >= 16;
    const int  b   = isQ ? (blk - 16) >> 1 : blk >> 2;
    const int  sub = isQ ? (blk - 16) & 1  : blk & 3;
    const float* src = (isQ ? x + b * N : xz + b * M) + sub * 2048;
    float2 v2 = *(const float2*)(src + t * 2);
    atomicAdd(&h[bucket_of(v2.x)], 1);
    atomicAdd(&h[bucket_of(v2.y)], 1);
    __syncthreads();
    part[blk * NB + t]        = h[t];
    part[blk * NB + 1024 + t] = h[1024 + t];
}

// K2: 536 blocks x 1024. Blocks 0..23 = scat (r0-verified 1024-thread scan
// structure over part totals + prior-sub offsets; block-local LDS ranking;
// slot ranges disjoint across blocks -> no inter-block atomics). Blocks
// 24..535 = transpose+cast z [B,C,M] -> zt[b][m][C] bf16 in ORIGINAL m order
// (r9-verified) — runs BESIDE scat, hiding its 24-block tail.
__global__ __launch_bounds__(1024) void work_kernel(
    const float* __restrict__ xz, const float* __restrict__ x,
    const float* __restrict__ z,  const int* __restrict__ part,
    int* __restrict__ bucket_start,    // [B][NB+1]
    float* __restrict__ xs,            // [B*M] sorted point coords
    int* __restrict__ iord,            // [B][M] sorted slot -> original m
    float* __restrict__ qcs,           // [B][N] sorted query coords
    int* __restrict__ qis,             // [B][N] sorted slot -> original n
    unsigned short* __restrict__ zt)   // [B*M][C] bf16, original order
{
    const int t    = threadIdx.x;
    const int blk  = blockIdx.x;
    const int lane = t & 63;
    const int w    = t >> 6;

    __shared__ int   base[NB];
    __shared__ int   cnt[NB];
    __shared__ int   wsum[16];
    __shared__ float tile[64][65];

    if (blk < 24) {
        const bool isQ = blk >= 16;
        const int  b   = isQ ? (blk - 16) >> 1 : blk >> 2;
        const int  sub = isQ ? (blk - 16) & 1  : blk & 3;
        const int  nsub = isQ ? NSUBQ : NSUBP;
        const int  pb0  = isQ ? 16 + b * 2 : b * 4;
        const float* src = (isQ ? x + b * N : xz + b * M) + sub * 2048;

        // buckets 2t, 2t+1: totals + prior-sub ("mine") counts from partials
        int tot0 = 0, tot1 = 0, mine0 = 0, mine1 = 0;
        for (int s_ = 0; s_ < nsub; ++s_) {
            const int v0 = part[(pb0 + s_) * NB + 2 * t];
            const int v1 = part[(pb0 + s_) * NB + 2 * t + 1];
            tot0 += v0; tot1 += v1;
            if (s_ < sub) { mine0 += v0; mine1 += v1; }
        }
        const int tsum = tot0 + tot1;
        int s = tsum;
        #pragma unroll
        for (int off = 1; off < 64; off <<= 1) {
            int up = __shfl_up(s, off, 64);
            if (lane >= off) s += up;
        }
        if (lane == 63) wsum[w] = s;
        cnt[t] = 0; cnt[t + 1024] = 0;
        __syncthreads();
        int woff = 0;
        for (int i = 0; i < w; ++i) woff += wsum[i];
        const int excl = woff + s - tsum;       // exclusive start of bucket 2t
        base[2 * t]     = excl + mine0;
        base[2 * t + 1] = excl + tot0 + mine1;
        if (!isQ && sub == 0) {
            bucket_start[b * (NB + 1) + 2 * t]     = excl;
            bucket_start[b * (NB + 1) + 2 * t + 1] = excl + tot0;
            if (t == 1023) bucket_start[b * (NB + 1) + NB] = woff + s;  // == M
        }
        __syncthreads();

        float2 v2 = *(const float2*)(src + t * 2);
        float vv[2] = {v2.x, v2.y};
        #pragma unroll
        for (int c = 0; c < 2; ++c) {
            const int k    = bucket_of(vv[c]);
            const int slot = base[k] + atomicAdd(&cnt[k], 1);
            const int orig = sub * 2048 + t * 2 + c;
            if (!isQ) {
                xs[b * M + slot]   = vv[c];
                iord[b * M + slot] = orig;
            } else {
                qcs[b * N + slot] = vv[c];
                qis[b * N + slot] = orig;
            }
        }
    } else {
        const int tix = blk - 24;          // 0..511
        const int b   = tix >> 7;
        const int m0  = (tix & 127) * 64;
        const int m   = t & 63;
        #pragma unroll
        for (int k = 0; k < 4; ++k) {
            int c = (t >> 6) + 16 * k;
            tile[c][m] = z[((size_t)b * C + c) * M + m0 + m];   // coalesced in m
        }
        __syncthreads();
        const int j  = t >> 4;             // row (point) 0..63
        const int c4 = t & 15;
        ushort4 v4;
        v4.x = f2bf(tile[c4 * 4 + 0][j]);
        v4.y = f2bf(tile[c4 * 4 + 1][j]);
        v4.z = f2bf(tile[c4 * 4 + 2][j]);
        v4.w = f2bf(tile[c4 * 4 + 3][j]);
        ((ushort4*)zt)[((size_t)b * M + m0 + j) * 16 + c4] = v4;  // coalesced
    }
}

// K3: one block per 16 sorted queries; 4 waves; mfma_f32_16x16x32_bf16.
// r9-verified: scalar superset window + iord/xs prefetch + indirect
// global_load_lds staging (per-lane global src, linear LDS dest).
__global__ __launch_bounds__(256) void gather_kernel(
    const float* __restrict__ log_scale,
    const int* __restrict__ bucket_start,
    const float* __restrict__ xs,
    const float* __restrict__ qcs,
    const int* __restrict__ qis,
    const int* __restrict__ iord,            // [B][M] slot -> m
    const unsigned short* __restrict__ zt,   // [B*M][C] bf16 original order
    float* __restrict__ out)                 // [B][N][C]
{
    const int t    = threadIdx.x;
    const int lane = t & 63;
    const int w    = t >> 6;            // wave 0..3 -> channels w*16..+15
    const int quad = lane >> 4;         // 0..3
    const int low4 = lane & 15;
    const int g  = blockIdx.x;
    const int b  = g >> 8;              // 256 groups per batch
    const int g0 = (g & 255) * QG;

    __shared__ unsigned short zr[64 * 64];   // 8 KB: 64 rows x 64 ch bf16
    __shared__ unsigned short wl[QG][72];    // 2.25 KB padded (144B rows)
    __shared__ float qcS[QG];
    __shared__ int   qiS[QG];

    const float ls   = log_scale[0];
    const float coef = -0.5f * __expf(-2.0f * ls);   // negative
    const float R    = sqrtf(CUT / (-coef));

    if (t < QG) {
        qcS[t] = qcs[b * N + g0 + t];
        qiS[t] = qis[b * N + g0 + t];
    }

    // scalar superset window — overlaps the qcS/qiS staging above
    const float qlo = qcs[b * N + g0];
    const float qhi = qcs[b * N + g0 + QG - 1];
    const int k0 = max(bucket_of(qlo - R) - 1, 0);
    const int k1 = min(bucket_of(qhi + R) + 1, NB - 1);
    const int s0 = bucket_start[b * (NB + 1) + k0];
    const int s1 = bucket_start[b * (NB + 1) + k1 + 1];
    const int e0 = s0 & ~63;                 // 64-aligned window; M%64==0
    const int e1 = (s1 + 63) & ~63;          // so [e0,e1) stays in [0,M]

    // weight-phase mapping: this lane computes queries qw, points pg*4..+3
    const int qw = w * 4 + quad;             // 0..15
    const int pg = low4;                     // point group (x4)

    const float* xsb = xs + b * M;
    const int* iordb = iord + b * M;
    const unsigned short* ztb = zt + (size_t)b * M * C;

    // prefetch chunk 0's indirection + coords
    const int ridx0 = (w * 2 + 0) * 8 + (lane >> 3);
    const int ridx1 = (w * 2 + 1) * 8 + (lane >> 3);
    int gmA = 0, gmB = 0;
    float4 xpA = {0.f, 0.f, 0.f, 0.f};
    if (e0 < e1) {
        gmA = iordb[e0 + ridx0];
        gmB = iordb[e0 + ridx1];
        xpA = *(const float4*)(xsb + e0 + pg * 4);
    }

    __syncthreads();                         // qcS/qiS staged
    const float qv = qcS[qw];

    f32x4 acc = {0.f, 0.f, 0.f, 0.f};

    for (int cs = e0; cs < e1; cs += 64) {
        __syncthreads();                 // zr/wl free from previous chunk
        // stage rows cs..cs+63: indirect 128B rows, 2 global_load_lds/wave
        {
            const unsigned short* gpA = ztb + (size_t)gmA * C + (lane & 7) * 8;
            const unsigned short* gpB = ztb + (size_t)gmB * C + (lane & 7) * 8;
            __builtin_amdgcn_global_load_lds(
                (const __attribute__((address_space(1))) void*)gpA,
                (__attribute__((address_space(3))) void*)(zr + (w * 2 + 0) * 512),
                16, 0, 0);
            __builtin_amdgcn_global_load_lds(
                (const __attribute__((address_space(1))) void*)gpB,
                (__attribute__((address_space(3))) void*)(zr + (w * 2 + 1) * 512),
                16, 0, 0);
        }
        // weights for THIS chunk from prefetched xpA (overlap the staging)
        {
            float d0 = qv - xpA.x, d1 = qv - xpA.y;
            float d2 = qv - xpA.z, d3 = qv - xpA.w;
            ushort4 wv;
            wv.x = f2bf(__expf(coef * d0 * d0));
            wv.y = f2bf(__expf(coef * d1 * d1));
            wv.z = f2bf(__expf(coef * d2 * d2));
            wv.w = f2bf(__expf(coef * d3 * d3));
            *(ushort4*)&wl[qw][pg * 4] = wv;
        }
        // prefetch chunk i+1's iord/xs (hides L2/L3 latency under MFMA)
        if (cs + 64 < e1) {
            gmA = iordb[cs + 64 + ridx0];
            gmB = iordb[cs + 64 + ridx1];
            xpA = *(const float4*)(xsb + cs + 64 + pg * 4);
        }
        __syncthreads();                 // zr staged + wl written
        // A = weights via b128 (padded rows), B = zr scalar u16, 2 MFMA
        #pragma unroll
        for (int kh = 0; kh < 2; ++kh) {
            short8 afrag = *(const short8*)&wl[low4][kh * 32 + quad * 8];
            short8 bfrag;
            #pragma unroll
            for (int j = 0; j < 8; ++j) {
                const int p = kh * 32 + quad * 8 + j;
                bfrag[j] = (short)zr[p * 64 + w * 16 + low4];
            }
            acc = __builtin_amdgcn_mfma_f32_16x16x32_bf16(afrag, bfrag, acc, 0, 0, 0);
        }
    }

    // D: row(query) = quad*4 + r, col(channel local) = low4
    #pragma unroll
    for (int r = 0; r < 4; ++r) {
        const int q = quad * 4 + r;
        out[((size_t)b * N + qiS[q]) * C + w * 16 + low4] = acc[r];
    }
}

extern "C" void kernel_launch(void* const* d_in, const int* in_sizes, int n_in,
                              void* d_out, int out_size, void* d_ws, size_t ws_size,
                              hipStream_t stream) {
    const float* xz = (const float*)d_in[0];  // [B,M,1]
    const float* z  = (const float*)d_in[1];  // [B,C,M]
    const float* x  = (const float*)d_in[2];  // [B,N,1]
    const float* ls = (const float*)d_in[3];  // scalar
    float* out = (float*)d_out;               // [B,N,C]

    char* ws = (char*)d_ws;
    size_t off = 0;
    auto alloc = [&](size_t bytes) { void* p = ws + off; off += (bytes + 255) & ~size_t(255); return p; };

    unsigned short* zt = (unsigned short*)alloc((size_t)B * M * C * sizeof(unsigned short)); // 4MB
    float* xs   = (float*)alloc(((size_t)B * M + 64) * sizeof(float));
    int*   iord = (int*)alloc((size_t)B * M * sizeof(int));
    float* qcs  = (float*)alloc((size_t)B * N * sizeof(float));
    int*   qis  = (int*)alloc((size_t)B * N * sizeof(int));
    int*   bst  = (int*)alloc((size_t)B * (NB + 1) * sizeof(int));
    int*   part = (int*)alloc((size_t)24 * NB * sizeof(int));

    hist_kernel<<<24, 1024, 0, stream>>>(xz, x, part);
    work_kernel<<<536, 1024, 0, stream>>>(xz, x, z, part, bst, xs, iord, qcs, qis, zt);
    gather_kernel<<<B * (N / QG), 256, 0, stream>>>(ls, bst, xs, qcs, qis, iord, zt, out);
}